// Round 1
// baseline (278.210 us; speedup 1.0000x reference)
//
#include <hip/hip_runtime.h>
#include <hip/hip_bf16.h>

// PolyAttentionBlock: B=16 N=1024 C=768 H=12 D=64. attn = a*s^2+b*s+c (no softmax).
// Pipeline: cvt(f32->bf16) -> QKV GEMM (bf16 MFMA) -> V transpose -> fused poly-attn -> proj GEMM.

typedef float  f32x4  __attribute__((ext_vector_type(4)));
typedef __bf16 bf16x8 __attribute__((ext_vector_type(8)));
typedef __bf16 bf16x4 __attribute__((ext_vector_type(4)));

#define AS1 __attribute__((address_space(1)))
#define AS3 __attribute__((address_space(3)))

__device__ __forceinline__ void gl16(const void* g, void* l) {
  // async global->LDS, 16B/lane; LDS dest = wave-uniform base + lane*16
  __builtin_amdgcn_global_load_lds((const AS1 unsigned int*)g, (AS3 unsigned int*)l, 16, 0, 0);
}

// ---------------- f32 -> bf16 cast ----------------
__global__ __launch_bounds__(256) void cvtk(const float* __restrict__ s,
                                            __bf16* __restrict__ d, int n) {
  int i = (blockIdx.x * 256 + threadIdx.x) * 4;
  if (i >= n) return;
  float4 v = *reinterpret_cast<const float4*>(s + i);
  bf16x4 o = { (__bf16)v.x, (__bf16)v.y, (__bf16)v.z, (__bf16)v.w };
  *reinterpret_cast<bf16x4*>(d + i) = o;
}

// ---------------- V transpose: qkv[B*N,2304] (v at col 1536+h*64+d) -> vT[B,H,D=64,N=1024] ----------------
__global__ __launch_bounds__(256) void vtransk(const __bf16* __restrict__ qkv,
                                               __bf16* __restrict__ vT) {
  int tid = blockIdx.x * 256 + threadIdx.x;      // 16*12*64*128 = 1572864 threads
  int ms = tid & 127;                            // m-slot (8 m's each)
  int d  = (tid >> 7) & 63;
  int bh = tid >> 13;                            // 0..191
  int b = bh / 12, h = bh - b * 12;
  const __bf16* base = qkv + (size_t)(b * 1024 + ms * 8) * 2304 + 1536 + h * 64 + d;
  bf16x8 v;
#pragma unroll
  for (int j = 0; j < 8; ++j) v[j] = base[(size_t)j * 2304];
  *reinterpret_cast<bf16x8*>(vT + ((size_t)bh * 64 + d) * 1024 + ms * 8) = v;
}

// ---------------- GEMM: out[M,Nn] = A[M,K] @ W[Nn,K]^T + bias ----------------
// m97 structure: 128x128 tile, BK=32, 4 waves (2x2 of 64x64), global_load_lds, linear LDS.
template <bool OB>  // OB: output bf16, else f32
__global__ __launch_bounds__(256) void gemmk(const __bf16* __restrict__ A,
                                             const __bf16* __restrict__ W,
                                             const float* __restrict__ bias,
                                             void* __restrict__ outp,
                                             int M, int Nn, int K, int ldo) {
  __shared__ __bf16 lA[128 * 32];  // 8KB, linear [row][32]
  __shared__ __bf16 lB[128 * 32];
  const int t = threadIdx.x, w = t >> 6, l = t & 63;
  const int l15 = l & 15, lg = l >> 4;
  const int row0 = blockIdx.x * 128, col0 = blockIdx.y * 128;
  const int rw = (w >> 1) * 64, cw = (w & 1) * 64;
  const int sr = l >> 2, sk = (l & 3) * 8;  // staging: row-in-16, k-elem offset

  const f32x4 zz = {0.f, 0.f, 0.f, 0.f};
  f32x4 acc[4][4];
#pragma unroll
  for (int m = 0; m < 4; ++m)
#pragma unroll
    for (int n = 0; n < 4; ++n) acc[m][n] = zz;

  for (int k0 = 0; k0 < K; k0 += 32) {
#pragma unroll
    for (int c = 0; c < 2; ++c) {
      int r = c * 64 + w * 16 + sr;
      gl16(A + (size_t)(row0 + r) * K + k0 + sk, (char*)lA + c * 4096 + w * 1024);
      gl16(W + (size_t)(col0 + r) * K + k0 + sk, (char*)lB + c * 4096 + w * 1024);
    }
    __syncthreads();  // drains vmcnt(0) then barrier
    bf16x8 af[4], bfr[4];
#pragma unroll
    for (int m = 0; m < 4; ++m)
      af[m] = *(const bf16x8*)((const char*)lA + (rw + m * 16 + l15) * 64 + lg * 16);
#pragma unroll
    for (int n = 0; n < 4; ++n)
      bfr[n] = *(const bf16x8*)((const char*)lB + (cw + n * 16 + l15) * 64 + lg * 16);
#pragma unroll
    for (int m = 0; m < 4; ++m)
#pragma unroll
      for (int n = 0; n < 4; ++n)
        acc[m][n] = __builtin_amdgcn_mfma_f32_16x16x32_bf16(af[m], bfr[n], acc[m][n], 0, 0, 0);
    __syncthreads();
  }

  float bv[4];
#pragma unroll
  for (int n = 0; n < 4; ++n) bv[n] = bias[col0 + cw + n * 16 + l15];

#pragma unroll
  for (int m = 0; m < 4; ++m)
#pragma unroll
    for (int n = 0; n < 4; ++n)
#pragma unroll
      for (int e = 0; e < 4; ++e) {
        int r  = row0 + rw + m * 16 + lg * 4 + e;   // C/D: col=lane&15, row=(lane>>4)*4+e
        int cc = col0 + cw + n * 16 + l15;
        float v = acc[m][n][e] + bv[n];
        if (OB) ((__bf16*)outp)[(size_t)r * ldo + cc] = (__bf16)v;
        else    ((float*)outp)[(size_t)r * ldo + cc] = v;
      }
}

// ---------------- fused poly attention ----------------
// grid (8 q-tiles, 192 bh), 256 thr. Per block: Q-tile 128 rows; loop 8 K/V m-tiles of 128.
// S=QK^T via MFMA (waves 2x2 over 128x128 S), poly in f32, P->LDS (bf16, swizzled), O += P@V.
__global__ __launch_bounds__(256) void attnk(const __bf16* __restrict__ qkv,
                                             const __bf16* __restrict__ vT,
                                             __bf16* __restrict__ o,
                                             const float* __restrict__ poly) {
  __shared__ __bf16 lK[128 * 64];   // 16KB  logical [krow][d=64], rows 128B, XOR-swizzled
  __shared__ __bf16 lV[64 * 128];   // 16KB  logical [d][m=128],   rows 256B, XOR-swizzled
  __shared__ __bf16 lP[128 * 128];  // 32KB  logical [qrow][m=128], rows 256B, XOR-swizzled
  const int t = threadIdx.x, w = t >> 6, l = t & 63;
  const int l15 = l & 15, lg = l >> 4;
  const int bh = blockIdx.y, b = bh / 12, h = bh - b * 12;
  const int q0 = blockIdx.x * 128;
  const float pa = poly[0], pb = poly[1], pc = poly[2];
  const int rw = (w >> 1) * 64, cw = (w & 1) * 64;  // wave's S sub-tile
  const f32x4 zz = {0.f, 0.f, 0.f, 0.f};

  // Q fragments held in registers for the whole block
  bf16x8 qf[4][2];
#pragma unroll
  for (int m = 0; m < 4; ++m)
#pragma unroll
    for (int kk = 0; kk < 2; ++kk)
      qf[m][kk] = *(const bf16x8*)(qkv + (size_t)(b * 1024 + q0 + rw + m * 16 + l15) * 2304 +
                                   h * 64 + kk * 32 + lg * 8);

  f32x4 oacc[2][4];
#pragma unroll
  for (int mf = 0; mf < 2; ++mf)
#pragma unroll
    for (int n = 0; n < 4; ++n) oacc[mf][n] = zz;

  for (int mt = 0; mt < 8; ++mt) {
    const int m0 = mt * 128;
    // stage K tile: phys slot l&7 holds logical slot (l&7)^(row&7); row&7 == l>>3
#pragma unroll
    for (int c = 0; c < 4; ++c) {
      int r = c * 32 + w * 8 + (l >> 3);
      gl16(qkv + (size_t)(b * 1024 + m0 + r) * 2304 + 768 + h * 64 + (((l & 7) ^ (l >> 3)) << 3),
           (char*)lK + c * 4096 + w * 1024);
    }
    // stage Vt tile: phys slot l&15 holds logical slot (l&15)^(row&7); row = c*16+w*4+lg
#pragma unroll
    for (int c = 0; c < 4; ++c) {
      int r = c * 16 + w * 4 + lg;
      gl16(vT + (size_t)(bh * 64 + r) * 1024 + m0 + (((l15 ^ (r & 7)) & 15) << 3),
           (char*)lV + c * 4096 + w * 1024);
    }
    __syncthreads();

    // S = Q K^T
    f32x4 sacc[4][4];
#pragma unroll
    for (int kk = 0; kk < 2; ++kk) {
#pragma unroll
      for (int n = 0; n < 4; ++n) {
        int r = cw + n * 16 + l15;
        int slot = kk * 4 + lg;
        bf16x8 kf = *(const bf16x8*)((const char*)lK + r * 128 + ((slot ^ (r & 7)) << 4));
#pragma unroll
        for (int m = 0; m < 4; ++m)
          sacc[m][n] = __builtin_amdgcn_mfma_f32_16x16x32_bf16(
              qf[m][kk], kf, kk == 0 ? zz : sacc[m][n], 0, 0, 0);
      }
    }
    // poly, write P (bf16) to swizzled LDS
#pragma unroll
    for (int m = 0; m < 4; ++m)
#pragma unroll
      for (int n = 0; n < 4; ++n)
#pragma unroll
        for (int e = 0; e < 4; ++e) {
          float s = sacc[m][n][e] * 0.125f;
          float p = (pa * s + pb) * s + pc;
          int row = rw + m * 16 + lg * 4 + e;
          int col = cw + n * 16 + l15;
          *(__bf16*)((char*)lP + row * 256 + ((((col >> 3) ^ (row & 7))) << 4) + ((col & 7) << 1)) =
              (__bf16)p;
        }
    __syncthreads();

    // O += P @ V   (per wave: 32 q-rows x 64 d)
#pragma unroll
    for (int kk = 0; kk < 4; ++kk) {
      bf16x8 vf[4];
#pragma unroll
      for (int n = 0; n < 4; ++n) {
        int r = n * 16 + l15;
        int slot = kk * 4 + lg;
        vf[n] = *(const bf16x8*)((const char*)lV + r * 256 + ((slot ^ (r & 7)) << 4));
      }
#pragma unroll
      for (int mf = 0; mf < 2; ++mf) {
        int row = w * 32 + mf * 16 + l15;
        int slot = kk * 4 + lg;
        bf16x8 pf = *(const bf16x8*)((const char*)lP + row * 256 + ((slot ^ (row & 7)) << 4));
#pragma unroll
        for (int n = 0; n < 4; ++n)
          oacc[mf][n] = __builtin_amdgcn_mfma_f32_16x16x32_bf16(pf, vf[n], oacc[mf][n], 0, 0, 0);
      }
    }
    __syncthreads();  // before next stage overwrites lK/lV
  }

  // epilogue: O -> [B*N, 768] bf16 (proj GEMM's A)
#pragma unroll
  for (int mf = 0; mf < 2; ++mf)
#pragma unroll
    for (int n = 0; n < 4; ++n)
#pragma unroll
      for (int e = 0; e < 4; ++e) {
        int row = q0 + w * 32 + mf * 16 + lg * 4 + e;
        int d = n * 16 + l15;
        o[(size_t)(b * 1024 + row) * 768 + h * 64 + d] = (__bf16)oacc[mf][n][e];
      }
}

// ---------------- launch ----------------
extern "C" void kernel_launch(void* const* d_in, const int* in_sizes, int n_in,
                              void* d_out, int out_size, void* d_ws, size_t ws_size,
                              hipStream_t stream) {
  const float* x      = (const float*)d_in[0];  // [16,1024,768]
  const float* w_qkv  = (const float*)d_in[1];  // [2304,768]
  const float* b_qkv  = (const float*)d_in[2];  // [2304]
  const float* w_proj = (const float*)d_in[3];  // [768,768]
  const float* b_proj = (const float*)d_in[4];  // [768]
  const float* poly   = (const float*)d_in[5];  // [3]

  char* ws = (char*)d_ws;
  __bf16* xb     = (__bf16*)(ws);                 // 16384x768   = 25165824 B
  __bf16* wqkvb  = (__bf16*)(ws + 25165824);      // 2304x768    =  3538944 B
  __bf16* wprojb = (__bf16*)(ws + 28704768);      // 768x768     =  1179648 B
  __bf16* qkvb   = (__bf16*)(ws + 29884416);      // 16384x2304  = 75497472 B
  __bf16* vtb    = (__bf16*)(ws + 105381888);     // 192x64x1024 = 25165824 B
  __bf16* ob     = (__bf16*)(ws + 130547712);     // 16384x768   = 25165824 B
  // total 155713536 B

  cvtk<<<12582912 / 1024, 256, 0, stream>>>(x, xb, 12582912);
  cvtk<<<1769472 / 1024, 256, 0, stream>>>(w_qkv, wqkvb, 1769472);
  cvtk<<<589824 / 1024, 256, 0, stream>>>(w_proj, wprojb, 589824);

  gemmk<true><<<dim3(128, 18), 256, 0, stream>>>(xb, wqkvb, b_qkv, qkvb, 16384, 2304, 768, 2304);
  vtransk<<<6144, 256, 0, stream>>>(qkvb, vtb);
  attnk<<<dim3(8, 192), 256, 0, stream>>>(qkvb, vtb, ob, poly);
  gemmk<false><<<dim3(128, 6), 256, 0, stream>>>(ob, wprojb, b_proj, d_out, 16384, 768, 768, 768);
}

// Round 2
// 249.623 us; speedup vs baseline: 1.1145x; 1.1145x over previous
//
#include <hip/hip_runtime.h>
#include <hip/hip_bf16.h>

// PolyAttentionBlock: B=16 N=1024 C=768 H=12 D=64. attn = a*s^2+b*s+c (no softmax).
// Pipeline: cvt(f32->bf16) -> QKV GEMM (bf16 MFMA) -> V transpose -> fused poly-attn -> proj GEMM.

typedef float  f32x4  __attribute__((ext_vector_type(4)));
typedef __bf16 bf16x8 __attribute__((ext_vector_type(8)));
typedef __bf16 bf16x4 __attribute__((ext_vector_type(4)));

#define AS1 __attribute__((address_space(1)))
#define AS3 __attribute__((address_space(3)))

__device__ __forceinline__ void gl16(const void* g, void* l) {
  // async global->LDS, 16B/lane; LDS dest = wave-uniform base + lane*16
  __builtin_amdgcn_global_load_lds((const AS1 unsigned int*)g, (AS3 unsigned int*)l, 16, 0, 0);
}

// ---------------- f32 -> bf16 cast ----------------
__global__ __launch_bounds__(256) void cvtk(const float* __restrict__ s,
                                            __bf16* __restrict__ d, int n) {
  int i = (blockIdx.x * 256 + threadIdx.x) * 4;
  if (i >= n) return;
  float4 v = *reinterpret_cast<const float4*>(s + i);
  bf16x4 o = { (__bf16)v.x, (__bf16)v.y, (__bf16)v.z, (__bf16)v.w };
  *reinterpret_cast<bf16x4*>(d + i) = o;
}

// ---------------- V transpose: qkv[B*N,2304] (v at col 1536+h*64+d) -> vT[B,H,D=64,N=1024] ----------------
__global__ __launch_bounds__(256) void vtransk(const __bf16* __restrict__ qkv,
                                               __bf16* __restrict__ vT) {
  int tid = blockIdx.x * 256 + threadIdx.x;      // 16*12*64*128 = 1572864 threads
  int ms = tid & 127;                            // m-slot (8 m's each)
  int d  = (tid >> 7) & 63;
  int bh = tid >> 13;                            // 0..191
  int b = bh / 12, h = bh - b * 12;
  const __bf16* base = qkv + (size_t)(b * 1024 + ms * 8) * 2304 + 1536 + h * 64 + d;
  bf16x8 v;
#pragma unroll
  for (int j = 0; j < 8; ++j) v[j] = base[(size_t)j * 2304];
  *reinterpret_cast<bf16x8*>(vT + ((size_t)bh * 64 + d) * 1024 + ms * 8) = v;
}

// ---------------- GEMM: out[M,Nn] = A[M,K] @ W[Nn,K]^T + bias ----------------
// m97 structure: 128x128 tile, BK=32, 4 waves (2x2 of 64x64), global_load_lds, linear LDS.
template <bool OB>  // OB: output bf16, else f32
__global__ __launch_bounds__(256) void gemmk(const __bf16* __restrict__ A,
                                             const __bf16* __restrict__ W,
                                             const float* __restrict__ bias,
                                             void* __restrict__ outp,
                                             int M, int Nn, int K, int ldo) {
  __shared__ __bf16 lA[128 * 32];  // 8KB, linear [row][32]
  __shared__ __bf16 lB[128 * 32];
  const int t = threadIdx.x, w = t >> 6, l = t & 63;
  const int l15 = l & 15, lg = l >> 4;
  const int row0 = blockIdx.x * 128, col0 = blockIdx.y * 128;
  const int rw = (w >> 1) * 64, cw = (w & 1) * 64;
  const int sr = l >> 2, sk = (l & 3) * 8;  // staging: row-in-16, k-elem offset

  const f32x4 zz = {0.f, 0.f, 0.f, 0.f};
  f32x4 acc[4][4];
#pragma unroll
  for (int m = 0; m < 4; ++m)
#pragma unroll
    for (int n = 0; n < 4; ++n) acc[m][n] = zz;

  for (int k0 = 0; k0 < K; k0 += 32) {
#pragma unroll
    for (int c = 0; c < 2; ++c) {
      int r = c * 64 + w * 16 + sr;
      gl16(A + (size_t)(row0 + r) * K + k0 + sk, (char*)lA + c * 4096 + w * 1024);
      gl16(W + (size_t)(col0 + r) * K + k0 + sk, (char*)lB + c * 4096 + w * 1024);
    }
    __syncthreads();  // drains vmcnt(0) then barrier
    bf16x8 af[4], bfr[4];
#pragma unroll
    for (int m = 0; m < 4; ++m)
      af[m] = *(const bf16x8*)((const char*)lA + (rw + m * 16 + l15) * 64 + lg * 16);
#pragma unroll
    for (int n = 0; n < 4; ++n)
      bfr[n] = *(const bf16x8*)((const char*)lB + (cw + n * 16 + l15) * 64 + lg * 16);
#pragma unroll
    for (int m = 0; m < 4; ++m)
#pragma unroll
      for (int n = 0; n < 4; ++n)
        acc[m][n] = __builtin_amdgcn_mfma_f32_16x16x32_bf16(af[m], bfr[n], acc[m][n], 0, 0, 0);
    __syncthreads();
  }

  float bv[4];
#pragma unroll
  for (int n = 0; n < 4; ++n) bv[n] = bias[col0 + cw + n * 16 + l15];

#pragma unroll
  for (int m = 0; m < 4; ++m)
#pragma unroll
    for (int n = 0; n < 4; ++n)
#pragma unroll
      for (int e = 0; e < 4; ++e) {
        int r  = row0 + rw + m * 16 + lg * 4 + e;   // C/D: col=lane&15, row=(lane>>4)*4+e
        int cc = col0 + cw + n * 16 + l15;
        float v = acc[m][n][e] + bv[n];
        if (OB) ((__bf16*)outp)[(size_t)r * ldo + cc] = (__bf16)v;
        else    ((float*)outp)[(size_t)r * ldo + cc] = v;
      }
}

// ---------------- fused poly attention (v2) ----------------
// grid 1536 blocks (XCD-chunked swizzle), 256 thr = 4 waves.
// Per block: 128 q-rows; loop 16 K/V m-tiles of 64.
// Swapped QK^T: sacc = mfma(K,Q) = S^T, so each thread holds 4 consecutive-m P
// values per fragment -> bf16x4 packed ds_write_b64 into per-wave-private lP.
// Each wave owns 32 q-rows (its own lP quadrant) -> no barrier between P-write and PV.
__global__ __launch_bounds__(256, 3) void attnk(const __bf16* __restrict__ qkv,
                                                const __bf16* __restrict__ vT,
                                                __bf16* __restrict__ o,
                                                const float* __restrict__ poly) {
  __shared__ __bf16 lK[64 * 64];   // 8KB  [m=64][d=64], 128B rows, XOR-swizzled (16B units ^ row&7)
  __shared__ __bf16 lV[64 * 64];   // 8KB  [d=64][m=64], 128B rows, XOR-swizzled
  __shared__ __bf16 lP[128 * 64];  // 16KB [q=128][m=64], 128B rows, XOR-swizzled; wave w owns rows w*32..+31
  const int t = threadIdx.x, w = t >> 6, l = t & 63;
  const int l15 = l & 15, lg = l >> 4;

  // XCD-chunked swizzle: hw dispatch id -> xcd = id&7; give each XCD a contiguous
  // chunk of logical ids so the 8 q-tiles of one bh share one XCD's L2.
  const int fid = blockIdx.y * 8 + blockIdx.x;       // 0..1535, hw dispatch order
  const int logical = (fid & 7) * 192 + (fid >> 3);
  const int bh = logical >> 3, q0 = (logical & 7) * 128;
  const int b = bh / 12, h = bh - b * 12;
  const float pa = poly[0], pb = poly[1], pc = poly[2];
  const f32x4 zz = {0.f, 0.f, 0.f, 0.f};

  // Q fragments (wave w owns q-rows w*32..w*32+31): qf[a][kk] = Q[w32+16a+l15][kk*32+8lg .. +7]
  bf16x8 qf[2][2];
#pragma unroll
  for (int a = 0; a < 2; ++a)
#pragma unroll
    for (int kk = 0; kk < 2; ++kk)
      qf[a][kk] = *(const bf16x8*)(qkv + (size_t)(b * 1024 + q0 + w * 32 + 16 * a + l15) * 2304 +
                                   h * 64 + kk * 32 + lg * 8);

  f32x4 oacc[2][4];
#pragma unroll
  for (int mf = 0; mf < 2; ++mf)
#pragma unroll
    for (int n = 0; n < 4; ++n) oacc[mf][n] = zz;

  const int srow = l >> 3;                     // staging row-in-segment (0..7)
  const int sunit = (l & 7) ^ (srow & 7);      // pre-swizzled source 16B-unit
  for (int mt = 0; mt < 16; ++mt) {
    const int m0 = mt * 64;
    // stage K tile (8 segs of 1KB; wave w does segs 2w, 2w+1). phys unit (l&7) of
    // row (8s+srow) must hold logical unit (l&7)^(row&7) -> pre-swizzle global src.
#pragma unroll
    for (int c = 0; c < 2; ++c) {
      int s = w * 2 + c;
      gl16(qkv + (size_t)(b * 1024 + m0 + 8 * s + srow) * 2304 + 768 + h * 64 + (sunit << 3),
           (char*)lK + s * 1024);
    }
#pragma unroll
    for (int c = 0; c < 2; ++c) {
      int s = w * 2 + c;
      gl16(vT + (size_t)(bh * 64 + 8 * s + srow) * 1024 + m0 + (sunit << 3),
           (char*)lV + s * 1024);
    }
    __syncthreads();

    // S^T = K Q^T : sacc[a][c] element = S[q = w32+16a+l15][m = 16c+4lg+e]
    f32x4 sacc[2][4];
#pragma unroll
    for (int kk = 0; kk < 2; ++kk) {
      bf16x8 kf[4];
#pragma unroll
      for (int c = 0; c < 4; ++c) {
        int r = 16 * c + l15;
        kf[c] = *(const bf16x8*)((const char*)lK + r * 128 + (((kk * 4 + lg) ^ (r & 7)) << 4));
      }
      __builtin_amdgcn_s_setprio(1);
#pragma unroll
      for (int a = 0; a < 2; ++a)
#pragma unroll
        for (int c = 0; c < 4; ++c)
          sacc[a][c] = __builtin_amdgcn_mfma_f32_16x16x32_bf16(
              kf[c], qf[a][kk], kk == 0 ? zz : sacc[a][c], 0, 0, 0);
      __builtin_amdgcn_s_setprio(0);
    }

    // poly -> packed bf16x4 -> one ds_write_b64 per fragment (own wave's lP rows)
#pragma unroll
    for (int a = 0; a < 2; ++a)
#pragma unroll
      for (int c = 0; c < 4; ++c) {
        int q = w * 32 + 16 * a + l15;
        int mb2 = 32 * c + 8 * lg;  // byte offset of m-base (2*(16c+4lg)), 8B-aligned
        bf16x4 pk;
#pragma unroll
        for (int e = 0; e < 4; ++e) {
          float s = sacc[a][c][e] * 0.125f;
          float p = (pa * s + pb) * s + pc;
          pk[e] = (__bf16)p;
        }
        *(bf16x4*)((char*)lP + q * 128 + (mb2 ^ ((q & 7) << 4))) = pk;
      }

    // O += P @ V (per wave: its 32 q-rows x 64 d); compiler inserts lgkmcnt for lP dep
#pragma unroll
    for (int kk = 0; kk < 2; ++kk) {
      bf16x8 vf[4];
#pragma unroll
      for (int nf = 0; nf < 4; ++nf) {
        int d = 16 * nf + l15;
        vf[nf] = *(const bf16x8*)((const char*)lV + d * 128 + (((kk * 4 + lg) ^ (d & 7)) << 4));
      }
      bf16x8 pf[2];
#pragma unroll
      for (int mf = 0; mf < 2; ++mf) {
        int q = w * 32 + 16 * mf + l15;
        pf[mf] = *(const bf16x8*)((const char*)lP + q * 128 + (((kk * 4 + lg) ^ (q & 7)) << 4));
      }
      __builtin_amdgcn_s_setprio(1);
#pragma unroll
      for (int mf = 0; mf < 2; ++mf)
#pragma unroll
        for (int nf = 0; nf < 4; ++nf)
          oacc[mf][nf] = __builtin_amdgcn_mfma_f32_16x16x32_bf16(pf[mf], vf[nf], oacc[mf][nf], 0, 0, 0);
      __builtin_amdgcn_s_setprio(0);
    }
    __syncthreads();  // protect lK/lV before next stage
  }

  // epilogue: O -> [B*N, 768] bf16 (proj GEMM's A)
#pragma unroll
  for (int mf = 0; mf < 2; ++mf)
#pragma unroll
    for (int nf = 0; nf < 4; ++nf)
#pragma unroll
      for (int e = 0; e < 4; ++e) {
        int row = q0 + w * 32 + 16 * mf + 4 * lg + e;
        int d = 16 * nf + l15;
        o[(size_t)(b * 1024 + row) * 768 + h * 64 + d] = (__bf16)oacc[mf][nf][e];
      }
}

// ---------------- launch ----------------
extern "C" void kernel_launch(void* const* d_in, const int* in_sizes, int n_in,
                              void* d_out, int out_size, void* d_ws, size_t ws_size,
                              hipStream_t stream) {
  const float* x      = (const float*)d_in[0];  // [16,1024,768]
  const float* w_qkv  = (const float*)d_in[1];  // [2304,768]
  const float* b_qkv  = (const float*)d_in[2];  // [2304]
  const float* w_proj = (const float*)d_in[3];  // [768,768]
  const float* b_proj = (const float*)d_in[4];  // [768]
  const float* poly   = (const float*)d_in[5];  // [3]

  char* ws = (char*)d_ws;
  __bf16* xb     = (__bf16*)(ws);                 // 16384x768   = 25165824 B
  __bf16* wqkvb  = (__bf16*)(ws + 25165824);      // 2304x768    =  3538944 B
  __bf16* wprojb = (__bf16*)(ws + 28704768);      // 768x768     =  1179648 B
  __bf16* qkvb   = (__bf16*)(ws + 29884416);      // 16384x2304  = 75497472 B
  __bf16* vtb    = (__bf16*)(ws + 105381888);     // 192x64x1024 = 25165824 B
  __bf16* ob     = (__bf16*)(ws + 130547712);     // 16384x768   = 25165824 B
  // total 155713536 B

  cvtk<<<12582912 / 1024, 256, 0, stream>>>(x, xb, 12582912);
  cvtk<<<1769472 / 1024, 256, 0, stream>>>(w_qkv, wqkvb, 1769472);
  cvtk<<<589824 / 1024, 256, 0, stream>>>(w_proj, wprojb, 589824);

  gemmk<true><<<dim3(128, 18), 256, 0, stream>>>(xb, wqkvb, b_qkv, qkvb, 16384, 2304, 768, 2304);
  vtransk<<<6144, 256, 0, stream>>>(qkvb, vtb);
  attnk<<<dim3(8, 192), 256, 0, stream>>>(qkvb, vtb, ob, poly);
  gemmk<false><<<dim3(128, 6), 256, 0, stream>>>(ob, wprojb, b_proj, d_out, 16384, 768, 768, 768);
}

// Round 3
// 193.457 us; speedup vs baseline: 1.4381x; 1.2903x over previous
//
#include <hip/hip_runtime.h>
#include <hip/hip_bf16.h>

// PolyAttentionBlock: B=16 N=1024 C=768 H=12 D=64. attn = a*s^2+b*s+c (no softmax).
// cvt(f32->bf16) -> QKV GEMM (256^2 8-phase, V written transposed) -> fused poly-attn -> proj GEMM.

typedef float  f32x4  __attribute__((ext_vector_type(4)));
typedef __bf16 bf16x8 __attribute__((ext_vector_type(8)));
typedef __bf16 bf16x4 __attribute__((ext_vector_type(4)));

#define AS1 __attribute__((address_space(1)))
#define AS3 __attribute__((address_space(3)))

__device__ __forceinline__ void gl16(const void* g, void* l) {
  // async global->LDS, 16B/lane; LDS dest = wave-uniform base + lane*16
  __builtin_amdgcn_global_load_lds((const AS1 unsigned int*)g, (AS3 unsigned int*)l, 16, 0, 0);
}

// ---------------- f32 -> bf16 cast ----------------
__global__ __launch_bounds__(256) void cvtk(const float* __restrict__ s,
                                            __bf16* __restrict__ d, int n) {
  int i = (blockIdx.x * 256 + threadIdx.x) * 4;
  if (i >= n) return;
  float4 v = *reinterpret_cast<const float4*>(s + i);
  bf16x4 o = { (__bf16)v.x, (__bf16)v.y, (__bf16)v.z, (__bf16)v.w };
  *reinterpret_cast<bf16x4*>(d + i) = o;
}

// ---------------- 256x256 8-phase GEMM: out[M,Nn] = A[M,K] @ W[Nn,K]^T + bias ----------------
// 512 thr = 8 waves (2M x 4N), BK=64, LDS 128KB (2 dbuf x (A 32KB + B 32KB)), XOR-swizzled.
// Per iteration: 8 phases, 2 K-tiles. Counted vmcnt(6) at phases 4/8 only (T3+T4); T5 setprio.
// MODE 0: bf16 out; col>=1536 (V part) stored transposed to vout[B,H,64,1024]. MODE 1: f32 out.
template <int MODE>
__global__ __launch_bounds__(512, 2) void gemm256k(
    const __bf16* __restrict__ A, const __bf16* __restrict__ W,
    const float* __restrict__ bias, void* __restrict__ outp,
    __bf16* __restrict__ vout, int K, int nbx, int chunk, int ldo) {
  __shared__ char lds[131072];  // buf b: A at b*65536, B at b*65536+32768; rows 128B
  const int t = threadIdx.x, w = t >> 6, l = t & 63;
  const int l15 = l & 15, lg = l >> 4;
  const int wm = w >> 2, wn = w & 3;       // wave grid 2x4; wave tile 128r x 64c
  const int lr = l >> 3, sw = l & 7;       // staging row-in-8, phys 16B-unit

  // bijective XCD-chunked swizzle (nblocks % 8 == 0)
  const int fid = blockIdx.x;
  const int logical = (fid & 7) * chunk + (fid >> 3);
  const int bx = logical % nbx, by = logical / nbx;
  const int row0 = bx * 256, col0 = by * 256;

  const f32x4 zz = {0.f, 0.f, 0.f, 0.f};
  f32x4 acc[8][4];
#pragma unroll
  for (int m = 0; m < 8; ++m)
#pragma unroll
    for (int n = 0; n < 4; ++n) acc[m][n] = zz;
  bf16x8 af[2][2], bfr[4][2];

// stage one A-quarter (rows {Q*32..+31} u {128+Q*32..+31}) of K-tile KT into buf BUF
#define STA(BUF, Q, KT)                                                               \
  do {                                                                                \
    const int rr_ = (w < 4 ? (Q)*32 + w * 8 : 128 + (Q)*32 + (w & 3) * 8) + lr;       \
    gl16(A + (size_t)(row0 + rr_) * K + (KT)*64 + ((sw ^ (rr_ & 7)) << 3),            \
         lds + (BUF)*65536 +                                                          \
             (w < 4 ? (Q)*4096 + w * 1024 : 16384 + (Q)*4096 + (w & 3) * 1024));      \
  } while (0)
// stage B 64-row chunk C of K-tile KT into buf BUF
#define STB(BUF, C, KT)                                                               \
  do {                                                                                \
    const int rr_ = (C)*64 + w * 8 + lr;                                              \
    gl16(W + (size_t)(col0 + rr_) * K + (KT)*64 + ((sw ^ (rr_ & 7)) << 3),            \
         lds + (BUF)*65536 + 32768 + (C)*8192 + w * 1024);                            \
  } while (0)
// ds-read A-frags for m-reps {2*MQ, 2*MQ+1}, both k-frags
#define RDA(BUF, MQ)                                                                  \
  do {                                                                                \
    _Pragma("unroll") for (int j = 0; j < 2; ++j) {                                   \
      const int ra_ = wm * 128 + (2 * (MQ) + j) * 16 + l15;                           \
      _Pragma("unroll") for (int kf = 0; kf < 2; ++kf)                                \
          af[j][kf] = *(const bf16x8*)((const char*)lds + (BUF)*65536 + ra_ * 128 +   \
                                       (((kf * 4 + lg) ^ (ra_ & 7)) << 4));           \
    }                                                                                 \
  } while (0)
// ds-read all B-frags (held in regs across 4 phases)
#define RDB(BUF)                                                                      \
  do {                                                                                \
    _Pragma("unroll") for (int n = 0; n < 4; ++n) {                                   \
      const int rb_ = wn * 64 + n * 16 + l15;                                         \
      _Pragma("unroll") for (int kf = 0; kf < 2; ++kf)                                \
          bfr[n][kf] = *(const bf16x8*)((const char*)lds + (BUF)*65536 + 32768 +      \
                                        rb_ * 128 + (((kf * 4 + lg) ^ (rb_ & 7)) << 4)); \
    }                                                                                 \
  } while (0)
#define MF16(MQ)                                                                      \
  do {                                                                                \
    __builtin_amdgcn_s_setprio(1);                                                    \
    _Pragma("unroll") for (int j = 0; j < 2; ++j)                                     \
        _Pragma("unroll") for (int n = 0; n < 4; ++n)                                 \
            _Pragma("unroll") for (int kf = 0; kf < 2; ++kf)                          \
                acc[2 * (MQ) + j][n] = __builtin_amdgcn_mfma_f32_16x16x32_bf16(       \
                    af[j][kf], bfr[n][kf], acc[2 * (MQ) + j][n], 0, 0, 0);            \
    __builtin_amdgcn_s_setprio(0);                                                    \
  } while (0)
#define BAR                                                                           \
  __builtin_amdgcn_sched_barrier(0);                                                  \
  __builtin_amdgcn_s_barrier();                                                       \
  __builtin_amdgcn_sched_barrier(0)

  // prologue: K-tile 0 -> buf0 (8 calls), K-tile 1 -> buf1 first 6 calls
  STA(0, 0, 0); STB(0, 0, 0); STA(0, 1, 0); STB(0, 1, 0);
  STA(0, 2, 0); STB(0, 2, 0); STA(0, 3, 0); STB(0, 3, 0);
  STA(1, 0, 1); STB(1, 0, 1); STA(1, 1, 1); STB(1, 1, 1); STA(1, 2, 1); STB(1, 2, 1);
  asm volatile("s_waitcnt vmcnt(6)" ::: "memory");
  BAR;

  const int NI = K >> 7;  // iterations (2 K-tiles each)
  for (int i = 0; i < NI; ++i) {
    const bool last = (i == NI - 1);
    const int t1 = 2 * i + 1, t2 = 2 * i + 2, t3 = 2 * i + 3;
    // ph1: compute buf0 mq0; stage buf1's last calls of K-tile t1
    RDA(0, 0); RDB(0);
    STA(1, 3, t1); STB(1, 3, t1);
    BAR; MF16(0); BAR;
    // ph2
    RDA(0, 1);
    if (!last) { STA(0, 0, t2); STB(0, 0, t2); }
    BAR; MF16(1); BAR;
    // ph3
    RDA(0, 2);
    if (!last) { STA(0, 1, t2); STB(0, 1, t2); }
    BAR; MF16(2); BAR;
    // ph4 + gate
    RDA(0, 3);
    if (!last) { STA(0, 2, t2); STB(0, 2, t2); }
    if (last) { asm volatile("s_waitcnt vmcnt(0)" ::: "memory"); }
    else      { asm volatile("s_waitcnt vmcnt(6)" ::: "memory"); }
    BAR; MF16(3); BAR;
    // ph5: compute buf1 mq0
    RDA(1, 0); RDB(1);
    if (!last) { STA(0, 3, t2); STB(0, 3, t2); }
    BAR; MF16(0); BAR;
    // ph6
    RDA(1, 1);
    if (!last) { STA(1, 0, t3); STB(1, 0, t3); }
    BAR; MF16(1); BAR;
    // ph7
    RDA(1, 2);
    if (!last) { STA(1, 1, t3); STB(1, 1, t3); }
    BAR; MF16(2); BAR;
    // ph8 + gate
    RDA(1, 3);
    if (!last) { STA(1, 2, t3); STB(1, 2, t3); }
    if (!last) { asm volatile("s_waitcnt vmcnt(6)" ::: "memory"); }
    BAR; MF16(3); BAR;
  }

  // epilogue
  float bv[4];
#pragma unroll
  for (int n = 0; n < 4; ++n) bv[n] = bias[col0 + wn * 64 + n * 16 + l15];

  if (MODE == 0 && col0 >= 1536) {
    // V columns -> vout[B,H,64,1024] transposed; e-direction is contiguous in vout
#pragma unroll
    for (int m = 0; m < 8; ++m)
#pragma unroll
      for (int n = 0; n < 4; ++n) {
        const int cv = col0 + wn * 64 + n * 16 + l15 - 1536;
        const int h = cv >> 6, d = cv & 63;
        const int row = row0 + wm * 128 + m * 16 + lg * 4;
        const int b = row >> 10, nn = row & 1023;
        bf16x4 pk;
#pragma unroll
        for (int e = 0; e < 4; ++e) pk[e] = (__bf16)(acc[m][n][e] + bv[n]);
        *(bf16x4*)(vout + (((size_t)(b * 12 + h)) << 16) + (d << 10) + nn) = pk;
      }
  } else {
#pragma unroll
    for (int m = 0; m < 8; ++m)
#pragma unroll
      for (int n = 0; n < 4; ++n)
#pragma unroll
        for (int e = 0; e < 4; ++e) {
          const int r = row0 + wm * 128 + m * 16 + lg * 4 + e;
          const int cc = col0 + wn * 64 + n * 16 + l15;
          const float v = acc[m][n][e] + bv[n];
          if (MODE == 0) ((__bf16*)outp)[(size_t)r * ldo + cc] = (__bf16)v;
          else           ((float*)outp)[(size_t)r * ldo + cc] = v;
        }
  }
#undef STA
#undef STB
#undef RDA
#undef RDB
#undef MF16
#undef BAR
}

// ---------------- fused poly attention ----------------
// grid 1536 blocks (XCD-chunked swizzle), 256 thr = 4 waves; KVBLK=64, 16 tiles.
// Swapped QK^T -> per-thread consecutive-m P -> packed bf16x4 ds_write into per-wave lP.
__global__ __launch_bounds__(256, 3) void attnk(const __bf16* __restrict__ qkv,
                                                const __bf16* __restrict__ vT,
                                                __bf16* __restrict__ o,
                                                const float* __restrict__ poly) {
  __shared__ __bf16 lK[64 * 64];   // 8KB  [m][d=64], 128B rows, XOR-swizzled
  __shared__ __bf16 lV[64 * 64];   // 8KB  [d][m=64], 128B rows, XOR-swizzled
  __shared__ __bf16 lP[128 * 64];  // 16KB [q][m=64], 128B rows, XOR-swizzled; wave w owns rows w*32..+31
  const int t = threadIdx.x, w = t >> 6, l = t & 63;
  const int l15 = l & 15, lg = l >> 4;

  const int fid = blockIdx.y * 8 + blockIdx.x;       // 0..1535
  const int logical = (fid & 7) * 192 + (fid >> 3);
  const int bh = logical >> 3, q0 = (logical & 7) * 128;
  const int b = bh / 12, h = bh - b * 12;
  const float pa = poly[0], pb = poly[1], pc = poly[2];
  const f32x4 zz = {0.f, 0.f, 0.f, 0.f};

  bf16x8 qf[2][2];
#pragma unroll
  for (int a = 0; a < 2; ++a)
#pragma unroll
    for (int kk = 0; kk < 2; ++kk)
      qf[a][kk] = *(const bf16x8*)(qkv + (size_t)(b * 1024 + q0 + w * 32 + 16 * a + l15) * 2304 +
                                   h * 64 + kk * 32 + lg * 8);

  f32x4 oacc[2][4];
#pragma unroll
  for (int mf = 0; mf < 2; ++mf)
#pragma unroll
    for (int n = 0; n < 4; ++n) oacc[mf][n] = zz;

  const int srow = l >> 3;
  const int sunit = (l & 7) ^ (srow & 7);
  for (int mt = 0; mt < 16; ++mt) {
    const int m0 = mt * 64;
#pragma unroll
    for (int c = 0; c < 2; ++c) {
      int s = w * 2 + c;
      gl16(qkv + (size_t)(b * 1024 + m0 + 8 * s + srow) * 2304 + 768 + h * 64 + (sunit << 3),
           (char*)lK + s * 1024);
    }
#pragma unroll
    for (int c = 0; c < 2; ++c) {
      int s = w * 2 + c;
      gl16(vT + (size_t)(bh * 64 + 8 * s + srow) * 1024 + m0 + (sunit << 3),
           (char*)lV + s * 1024);
    }
    __syncthreads();

    // S^T = K Q^T
    f32x4 sacc[2][4];
#pragma unroll
    for (int kk = 0; kk < 2; ++kk) {
      bf16x8 kf[4];
#pragma unroll
      for (int c = 0; c < 4; ++c) {
        int r = 16 * c + l15;
        kf[c] = *(const bf16x8*)((const char*)lK + r * 128 + (((kk * 4 + lg) ^ (r & 7)) << 4));
      }
      __builtin_amdgcn_s_setprio(1);
#pragma unroll
      for (int a = 0; a < 2; ++a)
#pragma unroll
        for (int c = 0; c < 4; ++c)
          sacc[a][c] = __builtin_amdgcn_mfma_f32_16x16x32_bf16(
              kf[c], qf[a][kk], kk == 0 ? zz : sacc[a][c], 0, 0, 0);
      __builtin_amdgcn_s_setprio(0);
    }

    // poly -> packed bf16x4 -> one ds_write_b64 per fragment
#pragma unroll
    for (int a = 0; a < 2; ++a)
#pragma unroll
      for (int c = 0; c < 4; ++c) {
        int q = w * 32 + 16 * a + l15;
        int mb2 = 32 * c + 8 * lg;
        bf16x4 pk;
#pragma unroll
        for (int e = 0; e < 4; ++e) {
          float s = sacc[a][c][e] * 0.125f;
          float p = (pa * s + pb) * s + pc;
          pk[e] = (__bf16)p;
        }
        *(bf16x4*)((char*)lP + q * 128 + (mb2 ^ ((q & 7) << 4))) = pk;
      }

    // O += P @ V
#pragma unroll
    for (int kk = 0; kk < 2; ++kk) {
      bf16x8 vf[4];
#pragma unroll
      for (int nf = 0; nf < 4; ++nf) {
        int d = 16 * nf + l15;
        vf[nf] = *(const bf16x8*)((const char*)lV + d * 128 + (((kk * 4 + lg) ^ (d & 7)) << 4));
      }
      bf16x8 pf[2];
#pragma unroll
      for (int mf = 0; mf < 2; ++mf) {
        int q = w * 32 + 16 * mf + l15;
        pf[mf] = *(const bf16x8*)((const char*)lP + q * 128 + (((kk * 4 + lg) ^ (q & 7)) << 4));
      }
      __builtin_amdgcn_s_setprio(1);
#pragma unroll
      for (int mf = 0; mf < 2; ++mf)
#pragma unroll
        for (int nf = 0; nf < 4; ++nf)
          oacc[mf][nf] = __builtin_amdgcn_mfma_f32_16x16x32_bf16(pf[mf], vf[nf], oacc[mf][nf], 0, 0, 0);
      __builtin_amdgcn_s_setprio(0);
    }
    __syncthreads();
  }

#pragma unroll
  for (int mf = 0; mf < 2; ++mf)
#pragma unroll
    for (int nf = 0; nf < 4; ++nf)
#pragma unroll
      for (int e = 0; e < 4; ++e) {
        int row = q0 + w * 32 + 16 * mf + 4 * lg + e;
        int d = 16 * nf + l15;
        o[(size_t)(b * 1024 + row) * 768 + h * 64 + d] = (__bf16)oacc[mf][nf][e];
      }
}

// ---------------- launch ----------------
extern "C" void kernel_launch(void* const* d_in, const int* in_sizes, int n_in,
                              void* d_out, int out_size, void* d_ws, size_t ws_size,
                              hipStream_t stream) {
  const float* x      = (const float*)d_in[0];  // [16,1024,768]
  const float* w_qkv  = (const float*)d_in[1];  // [2304,768]
  const float* b_qkv  = (const float*)d_in[2];  // [2304]
  const float* w_proj = (const float*)d_in[3];  // [768,768]
  const float* b_proj = (const float*)d_in[4];  // [768]
  const float* poly   = (const float*)d_in[5];  // [3]

  char* ws = (char*)d_ws;
  __bf16* xb     = (__bf16*)(ws);                 // 16384x768   = 25165824 B
  __bf16* wqkvb  = (__bf16*)(ws + 25165824);      // 2304x768    =  3538944 B
  __bf16* wprojb = (__bf16*)(ws + 28704768);      // 768x768     =  1179648 B
  __bf16* qkvb   = (__bf16*)(ws + 29884416);      // 16384x2304  = 75497472 B
  __bf16* vtb    = (__bf16*)(ws + 105381888);     // 192x64x1024 = 25165824 B
  __bf16* ob     = (__bf16*)(ws + 130547712);     // 16384x768   = 25165824 B

  cvtk<<<12582912 / 1024, 256, 0, stream>>>(x, xb, 12582912);
  cvtk<<<1769472 / 1024, 256, 0, stream>>>(w_qkv, wqkvb, 1769472);
  cvtk<<<589824 / 1024, 256, 0, stream>>>(w_proj, wprojb, 589824);

  // QKV: M=16384 (64 tiles) x N=2304 (9 tiles) = 576 blocks; V cols -> vtb transposed
  gemm256k<0><<<576, 512, 0, stream>>>(xb, wqkvb, b_qkv, qkvb, vtb, 768, 64, 72, 2304);
  attnk<<<dim3(8, 192), 256, 0, stream>>>(qkvb, vtb, ob, poly);
  // proj: M=16384 x N=768 (3 tiles) = 192 blocks
  gemm256k<1><<<192, 512, 0, stream>>>(ob, wprojb, b_proj, d_out, nullptr, 768, 64, 24, 768);
}

// Round 4
// 181.337 us; speedup vs baseline: 1.5342x; 1.0668x over previous
//
#include <hip/hip_runtime.h>
#include <hip/hip_bf16.h>

// PolyAttentionBlock: B=16 N=1024 C=768 H=12 D=64. attn = a*s^2+b*s+c (no softmax).
// cvt(f32->bf16) -> QKV GEMM (256^2 8-phase, V written transposed) -> fused poly-attn -> proj GEMM.

typedef float  f32x4  __attribute__((ext_vector_type(4)));
typedef __bf16 bf16x8 __attribute__((ext_vector_type(8)));
typedef __bf16 bf16x4 __attribute__((ext_vector_type(4)));

#define AS1 __attribute__((address_space(1)))
#define AS3 __attribute__((address_space(3)))

__device__ __forceinline__ void gl16(const void* g, void* l) {
  // async global->LDS, 16B/lane; LDS dest = wave-uniform base + lane*16
  __builtin_amdgcn_global_load_lds((const AS1 unsigned int*)g, (AS3 unsigned int*)l, 16, 0, 0);
}

// ---------------- f32 -> bf16 cast ----------------
__global__ __launch_bounds__(256) void cvtk(const float* __restrict__ s,
                                            __bf16* __restrict__ d, int n) {
  int i = (blockIdx.x * 256 + threadIdx.x) * 4;
  if (i >= n) return;
  float4 v = *reinterpret_cast<const float4*>(s + i);
  bf16x4 o = { (__bf16)v.x, (__bf16)v.y, (__bf16)v.z, (__bf16)v.w };
  *reinterpret_cast<bf16x4*>(d + i) = o;
}

// ---------------- 256x256 8-phase GEMM: out[M,Nn] = A[M,K] @ W[Nn,K]^T + bias ----------------
// 512 thr = 8 waves (2M x 4N), BK=64, LDS 128KB (2 dbuf x (A 32KB + B 32KB)), XOR-swizzled.
// Per iteration: 8 phases, 2 K-tiles. Counted vmcnt(6) at phases 4/8 only (T3+T4); T5 setprio.
// Phase skeleton per m201 template: {ds_read + stage} ; s_barrier ; lgkmcnt(0) ; MFMA ; s_barrier.
// NO sched_barrier(0) (m141: order-pinning regresses 874->510 TF).
// MODE 0: bf16 out; col>=1536 (V part) stored transposed to vout[B,H,64,1024]. MODE 1: f32 out.
template <int MODE>
__global__ __launch_bounds__(512, 2) void gemm256k(
    const __bf16* __restrict__ A, const __bf16* __restrict__ W,
    const float* __restrict__ bias, void* __restrict__ outp,
    __bf16* __restrict__ vout, int K, int nby, int chunk, int ldo) {
  __shared__ char lds[131072];  // buf b: A at b*65536, B at b*65536+32768; rows 128B
  const int t = threadIdx.x, w = t >> 6, l = t & 63;
  const int l15 = l & 15, lg = l >> 4;
  const int wm = w >> 2, wn = w & 3;       // wave grid 2x4; wave tile 128r x 64c
  const int lr = l >> 3, sw = l & 7;       // staging row-in-8, phys 16B-unit

  // bijective XCD-chunked swizzle (nblocks % 8 == 0); row-major chunks:
  // each XCD gets (chunk/nby) consecutive row-tiles x ALL col-tiles -> A panels
  // fetched once per XCD, W resident in L2.
  const int fid = blockIdx.x;
  const int logical = (fid & 7) * chunk + (fid >> 3);
  const int bx = logical / nby, by = logical % nby;
  const int row0 = bx * 256, col0 = by * 256;

  const f32x4 zz = {0.f, 0.f, 0.f, 0.f};
  f32x4 acc[8][4];
#pragma unroll
  for (int m = 0; m < 8; ++m)
#pragma unroll
    for (int n = 0; n < 4; ++n) acc[m][n] = zz;
  bf16x8 af[2][2], bfr[4][2];

// stage one A-quarter (rows {Q*32..+31} u {128+Q*32..+31}) of K-tile KT into buf BUF
#define STA(BUF, Q, KT)                                                               \
  do {                                                                                \
    const int rr_ = (w < 4 ? (Q)*32 + w * 8 : 128 + (Q)*32 + (w & 3) * 8) + lr;       \
    gl16(A + (size_t)(row0 + rr_) * K + (KT)*64 + ((sw ^ (rr_ & 7)) << 3),            \
         lds + (BUF)*65536 +                                                          \
             (w < 4 ? (Q)*4096 + w * 1024 : 16384 + (Q)*4096 + (w & 3) * 1024));      \
  } while (0)
// stage B 64-row chunk C of K-tile KT into buf BUF
#define STB(BUF, C, KT)                                                               \
  do {                                                                                \
    const int rr_ = (C)*64 + w * 8 + lr;                                              \
    gl16(W + (size_t)(col0 + rr_) * K + (KT)*64 + ((sw ^ (rr_ & 7)) << 3),            \
         lds + (BUF)*65536 + 32768 + (C)*8192 + w * 1024);                            \
  } while (0)
// ds-read A-frags for m-reps {2*MQ, 2*MQ+1}, both k-frags
#define RDA(BUF, MQ)                                                                  \
  do {                                                                                \
    _Pragma("unroll") for (int j = 0; j < 2; ++j) {                                   \
      const int ra_ = wm * 128 + (2 * (MQ) + j) * 16 + l15;                           \
      _Pragma("unroll") for (int kf = 0; kf < 2; ++kf)                                \
          af[j][kf] = *(const bf16x8*)((const char*)lds + (BUF)*65536 + ra_ * 128 +   \
                                       (((kf * 4 + lg) ^ (ra_ & 7)) << 4));           \
    }                                                                                 \
  } while (0)
// ds-read all B-frags (held in regs across 4 phases)
#define RDB(BUF)                                                                      \
  do {                                                                                \
    _Pragma("unroll") for (int n = 0; n < 4; ++n) {                                   \
      const int rb_ = wn * 64 + n * 16 + l15;                                         \
      _Pragma("unroll") for (int kf = 0; kf < 2; ++kf)                                \
          bfr[n][kf] = *(const bf16x8*)((const char*)lds + (BUF)*65536 + 32768 +      \
                                        rb_ * 128 + (((kf * 4 + lg) ^ (rb_ & 7)) << 4)); \
    }                                                                                 \
  } while (0)
#define MF16(MQ)                                                                      \
  do {                                                                                \
    __builtin_amdgcn_s_setprio(1);                                                    \
    _Pragma("unroll") for (int j = 0; j < 2; ++j)                                     \
        _Pragma("unroll") for (int n = 0; n < 4; ++n)                                 \
            _Pragma("unroll") for (int kf = 0; kf < 2; ++kf)                          \
                acc[2 * (MQ) + j][n] = __builtin_amdgcn_mfma_f32_16x16x32_bf16(       \
                    af[j][kf], bfr[n][kf], acc[2 * (MQ) + j][n], 0, 0, 0);            \
    __builtin_amdgcn_s_setprio(0);                                                    \
  } while (0)
#define BAR1 __builtin_amdgcn_s_barrier(); asm volatile("s_waitcnt lgkmcnt(0)" ::: "memory")
#define BAR2 __builtin_amdgcn_s_barrier()

  // prologue: K-tile 0 -> buf0 (8 calls), K-tile 1 -> buf1 first 6 calls
  STA(0, 0, 0); STB(0, 0, 0); STA(0, 1, 0); STB(0, 1, 0);
  STA(0, 2, 0); STB(0, 2, 0); STA(0, 3, 0); STB(0, 3, 0);
  STA(1, 0, 1); STB(1, 0, 1); STA(1, 1, 1); STB(1, 1, 1); STA(1, 2, 1); STB(1, 2, 1);
  asm volatile("s_waitcnt vmcnt(6)" ::: "memory");
  BAR2;

  const int NI = K >> 7;  // iterations (2 K-tiles each)
  for (int i = 0; i < NI; ++i) {
    const bool last = (i == NI - 1);
    const int t1 = 2 * i + 1, t2 = 2 * i + 2, t3 = 2 * i + 3;
    // ph1: compute buf0 mq0; stage buf1's last calls of K-tile t1
    RDA(0, 0); RDB(0);
    STA(1, 3, t1); STB(1, 3, t1);
    BAR1; MF16(0); BAR2;
    // ph2
    RDA(0, 1);
    if (!last) { STA(0, 0, t2); STB(0, 0, t2); }
    BAR1; MF16(1); BAR2;
    // ph3
    RDA(0, 2);
    if (!last) { STA(0, 1, t2); STB(0, 1, t2); }
    BAR1; MF16(2); BAR2;
    // ph4 + gate
    RDA(0, 3);
    if (!last) { STA(0, 2, t2); STB(0, 2, t2); }
    if (last) { asm volatile("s_waitcnt vmcnt(0)" ::: "memory"); }
    else      { asm volatile("s_waitcnt vmcnt(6)" ::: "memory"); }
    BAR1; MF16(3); BAR2;
    // ph5: compute buf1 mq0
    RDA(1, 0); RDB(1);
    if (!last) { STA(0, 3, t2); STB(0, 3, t2); }
    BAR1; MF16(0); BAR2;
    // ph6
    RDA(1, 1);
    if (!last) { STA(1, 0, t3); STB(1, 0, t3); }
    BAR1; MF16(1); BAR2;
    // ph7
    RDA(1, 2);
    if (!last) { STA(1, 1, t3); STB(1, 1, t3); }
    BAR1; MF16(2); BAR2;
    // ph8 + gate
    RDA(1, 3);
    if (!last) { STA(1, 2, t3); STB(1, 2, t3); }
    if (!last) { asm volatile("s_waitcnt vmcnt(6)" ::: "memory"); }
    BAR1; MF16(3); BAR2;
  }

  // epilogue
  float bv[4];
#pragma unroll
  for (int n = 0; n < 4; ++n) bv[n] = bias[col0 + wn * 64 + n * 16 + l15];

  if (MODE == 0 && col0 >= 1536) {
    // V columns -> vout[B,H,64,1024] transposed; e-direction is contiguous in vout
#pragma unroll
    for (int m = 0; m < 8; ++m)
#pragma unroll
      for (int n = 0; n < 4; ++n) {
        const int cv = col0 + wn * 64 + n * 16 + l15 - 1536;
        const int h = cv >> 6, d = cv & 63;
        const int row = row0 + wm * 128 + m * 16 + lg * 4;
        const int b = row >> 10, nn = row & 1023;
        bf16x4 pk;
#pragma unroll
        for (int e = 0; e < 4; ++e) pk[e] = (__bf16)(acc[m][n][e] + bv[n]);
        *(bf16x4*)(vout + (((size_t)(b * 12 + h)) << 16) + (d << 10) + nn) = pk;
      }
  } else {
#pragma unroll
    for (int m = 0; m < 8; ++m)
#pragma unroll
      for (int n = 0; n < 4; ++n)
#pragma unroll
        for (int e = 0; e < 4; ++e) {
          const int r = row0 + wm * 128 + m * 16 + lg * 4 + e;
          const int cc = col0 + wn * 64 + n * 16 + l15;
          const float v = acc[m][n][e] + bv[n];
          if (MODE == 0) ((__bf16*)outp)[(size_t)r * ldo + cc] = (__bf16)v;
          else           ((float*)outp)[(size_t)r * ldo + cc] = v;
        }
  }
#undef STA
#undef STB
#undef RDA
#undef RDB
#undef MF16
#undef BAR1
#undef BAR2
}

// ---------------- fused poly attention ----------------
// grid 1536 blocks (XCD-chunked swizzle), 256 thr = 4 waves; KVBLK=64, 16 tiles.
// Swapped QK^T -> per-thread consecutive-m P -> packed bf16x4 ds_write into per-wave lP.
__global__ __launch_bounds__(256, 3) void attnk(const __bf16* __restrict__ qkv,
                                                const __bf16* __restrict__ vT,
                                                __bf16* __restrict__ o,
                                                const float* __restrict__ poly) {
  __shared__ __bf16 lK[64 * 64];   // 8KB  [m][d=64], 128B rows, XOR-swizzled
  __shared__ __bf16 lV[64 * 64];   // 8KB  [d][m=64], 128B rows, XOR-swizzled
  __shared__ __bf16 lP[128 * 64];  // 16KB [q][m=64], 128B rows, XOR-swizzled; wave w owns rows w*32..+31
  const int t = threadIdx.x, w = t >> 6, l = t & 63;
  const int l15 = l & 15, lg = l >> 4;

  const int fid = blockIdx.y * 8 + blockIdx.x;       // 0..1535
  const int logical = (fid & 7) * 192 + (fid >> 3);
  const int bh = logical >> 3, q0 = (logical & 7) * 128;
  const int b = bh / 12, h = bh - b * 12;
  const float pa = poly[0], pb = poly[1], pc = poly[2];
  const f32x4 zz = {0.f, 0.f, 0.f, 0.f};

  bf16x8 qf[2][2];
#pragma unroll
  for (int a = 0; a < 2; ++a)
#pragma unroll
    for (int kk = 0; kk < 2; ++kk)
      qf[a][kk] = *(const bf16x8*)(qkv + (size_t)(b * 1024 + q0 + w * 32 + 16 * a + l15) * 2304 +
                                   h * 64 + kk * 32 + lg * 8);

  f32x4 oacc[2][4];
#pragma unroll
  for (int mf = 0; mf < 2; ++mf)
#pragma unroll
    for (int n = 0; n < 4; ++n) oacc[mf][n] = zz;

  const int srow = l >> 3;
  const int sunit = (l & 7) ^ (srow & 7);
  for (int mt = 0; mt < 16; ++mt) {
    const int m0 = mt * 64;
#pragma unroll
    for (int c = 0; c < 2; ++c) {
      int s = w * 2 + c;
      gl16(qkv + (size_t)(b * 1024 + m0 + 8 * s + srow) * 2304 + 768 + h * 64 + (sunit << 3),
           (char*)lK + s * 1024);
    }
#pragma unroll
    for (int c = 0; c < 2; ++c) {
      int s = w * 2 + c;
      gl16(vT + (size_t)(bh * 64 + 8 * s + srow) * 1024 + m0 + (sunit << 3),
           (char*)lV + s * 1024);
    }
    __syncthreads();

    // S^T = K Q^T
    f32x4 sacc[2][4];
#pragma unroll
    for (int kk = 0; kk < 2; ++kk) {
      bf16x8 kf[4];
#pragma unroll
      for (int c = 0; c < 4; ++c) {
        int r = 16 * c + l15;
        kf[c] = *(const bf16x8*)((const char*)lK + r * 128 + (((kk * 4 + lg) ^ (r & 7)) << 4));
      }
      __builtin_amdgcn_s_setprio(1);
#pragma unroll
      for (int a = 0; a < 2; ++a)
#pragma unroll
        for (int c = 0; c < 4; ++c)
          sacc[a][c] = __builtin_amdgcn_mfma_f32_16x16x32_bf16(
              kf[c], qf[a][kk], kk == 0 ? zz : sacc[a][c], 0, 0, 0);
      __builtin_amdgcn_s_setprio(0);
    }

    // poly -> packed bf16x4 -> one ds_write_b64 per fragment
#pragma unroll
    for (int a = 0; a < 2; ++a)
#pragma unroll
      for (int c = 0; c < 4; ++c) {
        int q = w * 32 + 16 * a + l15;
        int mb2 = 32 * c + 8 * lg;
        bf16x4 pk;
#pragma unroll
        for (int e = 0; e < 4; ++e) {
          float s = sacc[a][c][e] * 0.125f;
          float p = (pa * s + pb) * s + pc;
          pk[e] = (__bf16)p;
        }
        *(bf16x4*)((char*)lP + q * 128 + (mb2 ^ ((q & 7) << 4))) = pk;
      }

    // O += P @ V
#pragma unroll
    for (int kk = 0; kk < 2; ++kk) {
      bf16x8 vf[4];
#pragma unroll
      for (int nf = 0; nf < 4; ++nf) {
        int d = 16 * nf + l15;
        vf[nf] = *(const bf16x8*)((const char*)lV + d * 128 + (((kk * 4 + lg) ^ (d & 7)) << 4));
      }
      bf16x8 pf[2];
#pragma unroll
      for (int mf = 0; mf < 2; ++mf) {
        int q = w * 32 + 16 * mf + l15;
        pf[mf] = *(const bf16x8*)((const char*)lP + q * 128 + (((kk * 4 + lg) ^ (q & 7)) << 4));
      }
      __builtin_amdgcn_s_setprio(1);
#pragma unroll
      for (int mf = 0; mf < 2; ++mf)
#pragma unroll
        for (int nf = 0; nf < 4; ++nf)
          oacc[mf][nf] = __builtin_amdgcn_mfma_f32_16x16x32_bf16(pf[mf], vf[nf], oacc[mf][nf], 0, 0, 0);
      __builtin_amdgcn_s_setprio(0);
    }
    __syncthreads();
  }

#pragma unroll
  for (int mf = 0; mf < 2; ++mf)
#pragma unroll
    for (int nf = 0; nf < 4; ++nf)
#pragma unroll
      for (int e = 0; e < 4; ++e) {
        int row = q0 + w * 32 + 16 * mf + 4 * lg + e;
        int d = 16 * nf + l15;
        o[(size_t)(b * 1024 + row) * 768 + h * 64 + d] = (__bf16)oacc[mf][nf][e];
      }
}

// ---------------- launch ----------------
extern "C" void kernel_launch(void* const* d_in, const int* in_sizes, int n_in,
                              void* d_out, int out_size, void* d_ws, size_t ws_size,
                              hipStream_t stream) {
  const float* x      = (const float*)d_in[0];  // [16,1024,768]
  const float* w_qkv  = (const float*)d_in[1];  // [2304,768]
  const float* b_qkv  = (const float*)d_in[2];  // [2304]
  const float* w_proj = (const float*)d_in[3];  // [768,768]
  const float* b_proj = (const float*)d_in[4];  // [768]
  const float* poly   = (const float*)d_in[5];  // [3]

  char* ws = (char*)d_ws;
  __bf16* xb     = (__bf16*)(ws);                 // 16384x768   = 25165824 B
  __bf16* wqkvb  = (__bf16*)(ws + 25165824);      // 2304x768    =  3538944 B
  __bf16* wprojb = (__bf16*)(ws + 28704768);      // 768x768     =  1179648 B
  __bf16* qkvb   = (__bf16*)(ws + 29884416);      // 16384x2304  = 75497472 B
  __bf16* vtb    = (__bf16*)(ws + 105381888);     // 192x64x1024 = 25165824 B
  __bf16* ob     = (__bf16*)(ws + 130547712);     // 16384x768   = 25165824 B

  cvtk<<<12582912 / 1024, 256, 0, stream>>>(x, xb, 12582912);
  cvtk<<<1769472 / 1024, 256, 0, stream>>>(w_qkv, wqkvb, 1769472);
  cvtk<<<589824 / 1024, 256, 0, stream>>>(w_proj, wprojb, 589824);

  // QKV: M=16384 (64 tiles) x N=2304 (9 tiles) = 576 blocks; V cols -> vtb transposed
  gemm256k<0><<<576, 512, 0, stream>>>(xb, wqkvb, b_qkv, qkvb, vtb, 768, 9, 72, 2304);
  attnk<<<dim3(8, 192), 256, 0, stream>>>(qkvb, vtb, ob, poly);
  // proj: M=16384 x N=768 (3 tiles) = 192 blocks
  gemm256k<1><<<192, 512, 0, stream>>>(ob, wprojb, b_proj, d_out, nullptr, 768, 3, 24, 768);
}